// Round 9
// baseline (122.727 us; speedup 1.0000x reference)
//
#include <hip/hip_runtime.h>
#include <math.h>

constexpr int H  = 4096;
constexpr int H2 = 8192;

typedef float f32x4 __attribute__((ext_vector_type(4)));

__device__ __forceinline__ float dot4s(const f32x4 w, const f32x4 v) {
    return fmaf(w.x, v.x, fmaf(w.y, v.y, fmaf(w.z, v.z, w.w * v.w)));
}

// Wave specialization by gate: block = one output row, wave g computes gate
// g's full dot product. Waves 0,2 (f,C) use cacheable loads -> W_f/W_C stay
// L3-resident (256 MB = L3 capacity); waves 1,3 (i,o) use nontemporal loads
// -> pure HBM streams that never allocate in (or wait on) L3. Unlike R8,
// each wave is a single-tier stream, so the HBM and L3 streams self-pace
// independently instead of lockstepping at the slower rate.
__global__ __launch_bounds__(256, 8)
void lstm_step_kernel(const float* __restrict__ h_prev,
                      const float* __restrict__ c_prev,
                      const float* __restrict__ x_t,
                      const float* __restrict__ W_f, const float* __restrict__ b_f,
                      const float* __restrict__ W_i, const float* __restrict__ b_i,
                      const float* __restrict__ W_C, const float* __restrict__ b_C,
                      const float* __restrict__ W_o, const float* __restrict__ b_o,
                      float* __restrict__ out)
{
    __shared__ float part[4];

    const int row  = blockIdx.x;
    const int wid  = threadIdx.x >> 6;      // gate index: 0=f 1=i 2=C 3=o
    const int lane = threadIdx.x & 63;

    const float* Wg = (wid == 0) ? W_f : (wid == 1) ? W_i
                    : (wid == 2) ? W_C : W_o;
    const f32x4* wg = (const f32x4*)(Wg + (size_t)row * H2);
    const f32x4* hv = (const f32x4*)h_prev;
    // second-half z: gate C sees c_prev (reference quirk), f/i/o see x_t
    const f32x4* z2 = (wid == 2) ? (const f32x4*)c_prev : (const f32x4*)x_t;

    float s = 0.f;

    if ((wid & 1) == 0) {
        // gates f, C: cacheable -> L3-resident across replays
        for (int it = 0; it < 16; ++it) {
            const int c = it * 64 + lane;
            s += dot4s(wg[c], hv[c]);
        }
        for (int it = 0; it < 16; ++it) {
            const int c = it * 64 + lane;
            s += dot4s(wg[1024 + c], z2[c]);
        }
    } else {
        // gates i, o: nontemporal -> pure HBM stream, no L3 allocate
        for (int it = 0; it < 16; ++it) {
            const int c = it * 64 + lane;
            s += dot4s(__builtin_nontemporal_load(wg + c), hv[c]);
        }
        for (int it = 0; it < 16; ++it) {
            const int c = it * 64 + lane;
            s += dot4s(__builtin_nontemporal_load(wg + 1024 + c), z2[c]);
        }
    }

    #pragma unroll
    for (int off = 32; off > 0; off >>= 1)
        s += __shfl_down(s, off, 64);

    if (lane == 0) part[wid] = s;
    __syncthreads();

    if (threadIdx.x == 0) {
        const float f      = 1.f / (1.f + expf(-(part[0] + b_f[row])));
        const float ig     = 1.f / (1.f + expf(-(part[1] + b_i[row])));
        const float ctilde = tanhf(part[2] + b_C[row]);
        const float og     = 1.f / (1.f + expf(-(part[3] + b_o[row])));
        const float Cnew   = f * c_prev[row] + ig * ctilde;
        out[row]     = og * tanhf(Cnew);   // h_t
        out[H + row] = Cnew;               // C_t
    }
}

extern "C" void kernel_launch(void* const* d_in, const int* in_sizes, int n_in,
                              void* d_out, int out_size, void* d_ws, size_t ws_size,
                              hipStream_t stream) {
    const float* h_prev = (const float*)d_in[0];
    const float* c_prev = (const float*)d_in[1];
    const float* x_t    = (const float*)d_in[2];
    const float* W_f    = (const float*)d_in[3];
    const float* b_f    = (const float*)d_in[4];
    const float* W_i    = (const float*)d_in[5];
    const float* b_i    = (const float*)d_in[6];
    const float* W_C    = (const float*)d_in[7];
    const float* b_C    = (const float*)d_in[8];
    const float* W_o    = (const float*)d_in[9];
    const float* b_o    = (const float*)d_in[10];
    float* out = (float*)d_out;

    lstm_step_kernel<<<H, 256, 0, stream>>>(
        h_prev, c_prev, x_t, W_f, b_f, W_i, b_i, W_C, b_C, W_o, b_o, out);
}

// Round 10
// 81.085 us; speedup vs baseline: 1.5136x; 1.5136x over previous
//
#include <hip/hip_runtime.h>
#include <math.h>

constexpr int H  = 4096;
constexpr int H2 = 8192;

typedef float f32x4 __attribute__((ext_vector_type(4)));

__device__ __forceinline__ float dot4s(const f32x4 w, const f32x4 v) {
    return fmaf(w.x, v.x, fmaf(w.y, v.y, fmaf(w.z, v.z, w.w * v.w)));
}

// L3 partitioning (R8, best = 81.3 us = 512 MB / 6.30 TB/s = the m13 fabric
// ceiling): W_f/W_C cacheable -> L3-resident across graph replays (256 MB =
// exactly L3 capacity, no thrash); W_i/W_o via nontemporal loads (nt flag:
// no L3 allocate) -> clean HBM stream. The two tiers share the ~6.3 TB/s
// L2-fill fabric, so this partition saturates it; R9's wave-specialization
// decoupling attempt regressed (4x vector traffic + block barrier coupling).
__global__ __launch_bounds__(256, 4)
void lstm_step_kernel(const float* __restrict__ h_prev,
                      const float* __restrict__ c_prev,
                      const float* __restrict__ x_t,
                      const float* __restrict__ W_f, const float* __restrict__ b_f,
                      const float* __restrict__ W_i, const float* __restrict__ b_i,
                      const float* __restrict__ W_C, const float* __restrict__ b_C,
                      const float* __restrict__ W_o, const float* __restrict__ b_o,
                      float* __restrict__ out)
{
    const int gtid = blockIdx.x * blockDim.x + threadIdx.x;
    const int row  = gtid >> 6;
    const int lane = threadIdx.x & 63;
    if (row >= H) return;

    const f32x4* wf = (const f32x4*)(W_f + (size_t)row * H2);
    const f32x4* wi = (const f32x4*)(W_i + (size_t)row * H2);
    const f32x4* wc = (const f32x4*)(W_C + (size_t)row * H2);
    const f32x4* wo = (const f32x4*)(W_o + (size_t)row * H2);
    const f32x4* hv = (const f32x4*)h_prev;
    const f32x4* xv = (const f32x4*)x_t;
    const f32x4* cv = (const f32x4*)c_prev;

    float sf = 0.f, si = 0.f, sc = 0.f, so = 0.f;

    // ---- half 0: columns [0,H), z = h_prev for all four gates ----
    for (int it = 0; it < 16; ++it) {
        const int c = it * 64 + lane;
        const f32x4 z = hv[c];
        const f32x4 a = wf[c];                              // cacheable
        const f32x4 b = __builtin_nontemporal_load(wi + c); // NT -> HBM stream
        const f32x4 d = wc[c];                              // cacheable
        const f32x4 e = __builtin_nontemporal_load(wo + c); // NT -> HBM stream
        sf += dot4s(a, z);
        si += dot4s(b, z);
        sc += dot4s(d, z);
        so += dot4s(e, z);
    }

    // ---- half 1: columns [H,2H), z = x_t for f,i,o ; z = c_prev for C ----
    for (int it = 0; it < 16; ++it) {
        const int c = it * 64 + lane;
        const int w = 1024 + c;
        const f32x4 zx = xv[c];
        const f32x4 zc = cv[c];
        const f32x4 a = wf[w];
        const f32x4 b = __builtin_nontemporal_load(wi + w);
        const f32x4 d = wc[w];
        const f32x4 e = __builtin_nontemporal_load(wo + w);
        sf += dot4s(a, zx);
        si += dot4s(b, zx);
        sc += dot4s(d, zc);
        so += dot4s(e, zx);
    }

    #pragma unroll
    for (int off = 32; off > 0; off >>= 1) {
        sf += __shfl_down(sf, off, 64);
        si += __shfl_down(si, off, 64);
        sc += __shfl_down(sc, off, 64);
        so += __shfl_down(so, off, 64);
    }

    if (lane == 0) {
        const float f      = 1.f / (1.f + expf(-(sf + b_f[row])));
        const float ig     = 1.f / (1.f + expf(-(si + b_i[row])));
        const float ctilde = tanhf(sc + b_C[row]);
        const float og     = 1.f / (1.f + expf(-(so + b_o[row])));
        const float Cnew   = f * c_prev[row] + ig * ctilde;
        out[row]     = og * tanhf(Cnew);   // h_t
        out[H + row] = Cnew;               // C_t
    }
}

extern "C" void kernel_launch(void* const* d_in, const int* in_sizes, int n_in,
                              void* d_out, int out_size, void* d_ws, size_t ws_size,
                              hipStream_t stream) {
    const float* h_prev = (const float*)d_in[0];
    const float* c_prev = (const float*)d_in[1];
    const float* x_t    = (const float*)d_in[2];
    const float* W_f    = (const float*)d_in[3];
    const float* b_f    = (const float*)d_in[4];
    const float* W_i    = (const float*)d_in[5];
    const float* b_i    = (const float*)d_in[6];
    const float* W_C    = (const float*)d_in[7];
    const float* b_C    = (const float*)d_in[8];
    const float* W_o    = (const float*)d_in[9];
    const float* b_o    = (const float*)d_in[10];
    float* out = (float*)d_out;

    lstm_step_kernel<<<(H * 64) / 256, 256, 0, stream>>>(
        h_prev, c_prev, x_t, W_f, b_f, W_i, b_i, W_C, b_C, W_o, b_o, out);
}